// Round 5
// baseline (21206.297 us; speedup 1.0000x reference)
//
#include <hip/hip_runtime.h>
#include <hip/hip_bf16.h>

#define BB 32
#define TT 512
#define IND 375
#define DD 512
#define HH 8
#define HDD 64
#define LL 6
#define FFNN 1024
#define LATD 256
#define KCODES 512
#define DLL 4
#define DHH 512
#define DFFF 1024
#define OUTD 291
#define MTOK (BB*TT)   /* 16384 tokens */

// ---------------- RoPE tables (fp32) ----------------
__global__ void rope_table_k(float* __restrict__ cosb, float* __restrict__ sinb) {
  int idx = blockIdx.x * blockDim.x + threadIdx.x;
  if (idx >= TT * 32) return;
  int t = idx >> 5, i = idx & 31;
  float inv = powf(10000.0f, -(float)(2 * i) / 64.0f);
  float f = (float)t * inv;
  cosb[idx] = cosf(f);
  sinb[idx] = sinf(f);
}

// ---------------- fp32 GEMM, 64x64 tile, BK=16 ----------------
// EPI: 0 = bias only, 1 = bias + residual R, 2 = gelu(bias+acc)
template<int EPI>
__global__ __launch_bounds__(256) void gemm_k(const float* __restrict__ A,
                                              const float* __restrict__ W,
                                              const float* __restrict__ bias,
                                              const float* __restrict__ R,
                                              float* __restrict__ C,
                                              int M, int K, int N) {
  __shared__ float As[16][65];
  __shared__ float Bs[16][64];
  const int bn = blockIdx.x * 64;
  const int bm = blockIdx.y * 64;
  const int tid = threadIdx.x;
  const int tx = tid & 15, ty = tid >> 4;
  float acc[4][4] = {};

  for (int k0 = 0; k0 < K; k0 += 16) {
    {
      int r = tid >> 2, kk = (tid & 3) << 2;
      int gr = bm + r;
#pragma unroll
      for (int j = 0; j < 4; ++j) {
        int kg = k0 + kk + j;
        As[kk + j][r] = (gr < M && kg < K) ? A[(size_t)gr * K + kg] : 0.0f;
      }
    }
    {
      int kk = tid >> 4, nn = (tid & 15) << 2;
      int kg = k0 + kk;
#pragma unroll
      for (int j = 0; j < 4; ++j) {
        int ng = bn + nn + j;
        Bs[kk][nn + j] = (kg < K && ng < N) ? W[(size_t)kg * N + ng] : 0.0f;
      }
    }
    __syncthreads();
#pragma unroll
    for (int kk = 0; kk < 16; ++kk) {
      float a0[4], b0[4];
#pragma unroll
      for (int j = 0; j < 4; ++j) { a0[j] = As[kk][ty * 4 + j]; b0[j] = Bs[kk][tx * 4 + j]; }
#pragma unroll
      for (int ii = 0; ii < 4; ++ii)
#pragma unroll
        for (int jj = 0; jj < 4; ++jj)
          acc[ii][jj] += a0[ii] * b0[jj];
    }
    __syncthreads();
  }

#pragma unroll
  for (int ii = 0; ii < 4; ++ii) {
    int m = bm + ty * 4 + ii;
    if (m >= M) continue;
#pragma unroll
    for (int jj = 0; jj < 4; ++jj) {
      int n = bn + tx * 4 + jj;
      if (n >= N) continue;
      float v = acc[ii][jj] + bias[n];
      if (EPI == 1) v += R[(size_t)m * N + n];
      if (EPI == 2) v = 0.5f * v * (1.0f + erff(v * 0.70710678118654752f));
      C[(size_t)m * N + n] = v;
    }
  }
}

// ---------------- LayerNorm over D=512, wave per row ----------------
__global__ __launch_bounds__(256) void ln_k(const float* __restrict__ X,
                                            const float* __restrict__ s,
                                            const float* __restrict__ b,
                                            float* __restrict__ Y) {
  int wave = threadIdx.x >> 6, lane = threadIdx.x & 63;
  int row = blockIdx.x * 4 + wave;
  const float* x = X + (size_t)row * DD;
  float v[8];
  float sum = 0.0f;
#pragma unroll
  for (int j = 0; j < 8; ++j) { v[j] = x[lane + 64 * j]; sum += v[j]; }
#pragma unroll
  for (int o = 32; o; o >>= 1) sum += __shfl_xor(sum, o);
  float mean = sum * (1.0f / 512.0f);
  float var = 0.0f;
#pragma unroll
  for (int j = 0; j < 8; ++j) { float d = v[j] - mean; var += d * d; }
#pragma unroll
  for (int o = 32; o; o >>= 1) var += __shfl_xor(var, o);
  float inv = 1.0f / sqrtf(var * (1.0f / 512.0f) + 1e-5f);
  float* y = Y + (size_t)row * DD;
#pragma unroll
  for (int j = 0; j < 8; ++j) {
    int d = lane + 64 * j;
    y[d] = (v[j] - mean) * inv * s[d] + b[d];
  }
}

// ---------------- RoPE applied in-place to q and k sections of qkv ----------------
__global__ void rope_k(float* __restrict__ qkv, const float* __restrict__ cosb,
                       const float* __restrict__ sinb) {
  int idx = blockIdx.x * blockDim.x + threadIdx.x;  // B*T*2*H*32 = 8388608
  if (idx >= BB * TT * 2 * HH * 32) return;
  int i = idx & 31; idx >>= 5;
  int h = idx & 7;  idx >>= 3;
  int s = idx & 1;  idx >>= 1;   // 0 = q, 1 = k
  int t = idx & 511; idx >>= 9;
  int b = idx;
  size_t base = ((size_t)(b * TT + t)) * (3 * DD) + s * DD + h * HDD + 2 * i;
  float c = cosb[t * 32 + i], sn = sinb[t * 32 + i];
  float xe = qkv[base], xo = qkv[base + 1];
  qkv[base]     = xe * c - xo * sn;
  qkv[base + 1] = xe * sn + xo * c;
}

// ---------------- attention: block = (b, h, 16 q-rows) ----------------
__global__ __launch_bounds__(256) void attn_k(const float* __restrict__ qkv,
                                              float* __restrict__ out) {
  __shared__ float qs[16][65];
  __shared__ float kvs[64][65];
  __shared__ float sc[16][512];
  int bh = blockIdx.x >> 5;          // /32 q-tiles
  int qt = blockIdx.x & 31;
  int b = bh >> 3, h = bh & 7;
  int tid = threadIdx.x;
  const float* base = qkv + (size_t)b * TT * (3 * DD) + h * HDD;

  for (int e = tid; e < 16 * 64; e += 256) {
    int r = e >> 6, d = e & 63;
    qs[r][d] = base[(size_t)(qt * 16 + r) * (3 * DD) + d];
  }
  for (int kt = 0; kt < 8; ++kt) {
    __syncthreads();
    for (int e = tid; e < 64 * 64; e += 256) {
      int r = e >> 6, d = e & 63;
      kvs[r][d] = base[(size_t)(kt * 64 + r) * (3 * DD) + DD + d];
    }
    __syncthreads();
    for (int e = tid; e < 16 * 64; e += 256) {
      int r = e >> 6, c = e & 63;
      float acc = 0.0f;
#pragma unroll
      for (int d = 0; d < 64; ++d) acc += qs[r][d] * kvs[c][d];
      sc[r][kt * 64 + c] = acc * 0.125f;
    }
  }
  __syncthreads();
  int wave = tid >> 6, lane = tid & 63;
  for (int r = wave; r < 16; r += 4) {
    float vals[8];
    float m = -1e30f;
#pragma unroll
    for (int j = 0; j < 8; ++j) { vals[j] = sc[r][lane + 64 * j]; m = fmaxf(m, vals[j]); }
#pragma unroll
    for (int o = 32; o; o >>= 1) m = fmaxf(m, __shfl_xor(m, o));
    float sum = 0.0f;
#pragma unroll
    for (int j = 0; j < 8; ++j) { vals[j] = expf(vals[j] - m); sum += vals[j]; }
#pragma unroll
    for (int o = 32; o; o >>= 1) sum += __shfl_xor(sum, o);
    float inv = 1.0f / sum;
#pragma unroll
    for (int j = 0; j < 8; ++j) sc[r][lane + 64 * j] = vals[j] * inv;
  }
  float acc[4] = {0.f, 0.f, 0.f, 0.f};
  int w = wave, d = lane;
  for (int kt = 0; kt < 8; ++kt) {
    __syncthreads();
    for (int e = tid; e < 64 * 64; e += 256) {
      int r = e >> 6, dd = e & 63;
      kvs[r][dd] = base[(size_t)(kt * 64 + r) * (3 * DD) + 2 * DD + dd];
    }
    __syncthreads();
#pragma unroll
    for (int kk = 0; kk < 64; ++kk) {
      float vv = kvs[kk][d];
#pragma unroll
      for (int oi = 0; oi < 4; ++oi) acc[oi] += sc[w + 4 * oi][kt * 64 + kk] * vv;
    }
  }
#pragma unroll
  for (int oi = 0; oi < 4; ++oi) {
    int tok = b * TT + qt * 16 + w + 4 * oi;
    out[(size_t)tok * DD + h * HDD + d] = acc[oi];
  }
}

// ===== numpy pairwise-8 sum of squares of a 64-vector (strict fp32 order) =====
__device__ __forceinline__ float npsumsq64(const float* __restrict__ a) {
  float r0 = __fmul_rn(a[0], a[0]), r1 = __fmul_rn(a[1], a[1]);
  float r2 = __fmul_rn(a[2], a[2]), r3 = __fmul_rn(a[3], a[3]);
  float r4 = __fmul_rn(a[4], a[4]), r5 = __fmul_rn(a[5], a[5]);
  float r6 = __fmul_rn(a[6], a[6]), r7 = __fmul_rn(a[7], a[7]);
#pragma unroll
  for (int i = 8; i < 64; i += 8) {
    r0 = __fadd_rn(r0, __fmul_rn(a[i + 0], a[i + 0]));
    r1 = __fadd_rn(r1, __fmul_rn(a[i + 1], a[i + 1]));
    r2 = __fadd_rn(r2, __fmul_rn(a[i + 2], a[i + 2]));
    r3 = __fadd_rn(r3, __fmul_rn(a[i + 3], a[i + 3]));
    r4 = __fadd_rn(r4, __fmul_rn(a[i + 4], a[i + 4]));
    r5 = __fadd_rn(r5, __fmul_rn(a[i + 5], a[i + 5]));
    r6 = __fadd_rn(r6, __fmul_rn(a[i + 6], a[i + 6]));
    r7 = __fadd_rn(r7, __fmul_rn(a[i + 7], a[i + 7]));
  }
  return __fadd_rn(__fadd_rn(__fadd_rn(r0, r1), __fadd_rn(r2, r3)),
                   __fadd_rn(__fadd_rn(r4, r5), __fadd_rn(r6, r7)));
}

// ===== VQ fp32 numpy-formula argmin: d = (S1 - 2*(z.c)) + S2, wave per chunk =====
__global__ __launch_bounds__(256) void vq32_k(const float* __restrict__ Z,
                                              const float* __restrict__ CB,
                                              int* __restrict__ idxOut) {
  __shared__ float zf[4][64];
  int wv = threadIdx.x >> 6, ln = threadIdx.x & 63;
  int row = blockIdx.x * 4 + wv;
  zf[wv][ln] = Z[(size_t)row * 64 + ln];
  __syncthreads();

  const float S1 = npsumsq64(zf[wv]);   // redundant per-lane, deterministic

  float bv = 3.4e38f;
  int bi = 0x7fffffff;
#pragma unroll
  for (int j = 0; j < 8; ++j) {
    int k = j * 64 + ln;
    const float* crow = CB + (size_t)k * 64;
    // z . c : sequential FMA chain (BLAS-class order)
    float g = 0.0f;
#pragma unroll
    for (int d = 0; d < 64; ++d) g = __builtin_fmaf(zf[wv][d], crow[d], g);
    float S2 = npsumsq64(crow);
    float d32 = __fadd_rn(__fsub_rn(S1, __fmul_rn(2.0f, g)), S2);
    if (d32 < bv || (d32 == bv && k < bi)) { bv = d32; bi = k; }
  }
#pragma unroll
  for (int o = 32; o; o >>= 1) {
    float ov = __shfl_xor(bv, o);
    int oi = __shfl_xor(bi, o);
    if (ov < bv || (ov == bv && oi < bi)) { bv = ov; bi = oi; }
  }
  if (ln == 0) idxOut[row] = bi;
}

// ===== straight-through gather: st = z + (c - z), fp32 faithful =====
__global__ void stgather_k(const float* __restrict__ Z, const float* __restrict__ CB,
                           const int* __restrict__ idx, float* __restrict__ Q) {
  int e = blockIdx.x * blockDim.x + threadIdx.x;
  if (e >= MTOK * LATD) return;
  int chunk = e >> 6, d = e & 63;
  int k = idx[chunk] & (KCODES - 1);   // defensive range mask
  float z = Z[e];
  float c = CB[(size_t)k * 64 + d];
  Q[e] = __fadd_rn(z, __fsub_rn(c, z));
}

static inline dim3 gemm_grid(int M, int N) { return dim3((N + 63) / 64, (M + 63) / 64); }

extern "C" void kernel_launch(void* const* d_in, const int* in_sizes, int n_in,
                              void* d_out, int out_size, void* d_ws, size_t ws_size,
                              hipStream_t stream) {
  const float* x        = (const float*)d_in[0];
  const float* in_w     = (const float*)d_in[1];
  const float* in_b     = (const float*)d_in[2];
  const float* ln1_s    = (const float*)d_in[3];
  const float* ln1_b    = (const float*)d_in[4];
  const float* qkv_w    = (const float*)d_in[5];
  const float* qkv_b    = (const float*)d_in[6];
  const float* aout_w   = (const float*)d_in[7];
  const float* aout_b   = (const float*)d_in[8];
  const float* ln2_s    = (const float*)d_in[9];
  const float* ln2_b    = (const float*)d_in[10];
  const float* ff1_w    = (const float*)d_in[11];
  const float* ff1_b    = (const float*)d_in[12];
  const float* ff2_w    = (const float*)d_in[13];
  const float* ff2_b    = (const float*)d_in[14];
  const float* lat_w    = (const float*)d_in[15];
  const float* lat_b    = (const float*)d_in[16];
  const float* codebook = (const float*)d_in[17];
  const float* unlat_w  = (const float*)d_in[18];
  const float* unlat_b  = (const float*)d_in[19];
  const float* dln_s    = (const float*)d_in[20];
  const float* dln_b    = (const float*)d_in[21];
  const float* dff1_w   = (const float*)d_in[22];
  const float* dff1_b   = (const float*)d_in[23];
  const float* dff2_w   = (const float*)d_in[24];
  const float* dff2_b   = (const float*)d_in[25];
  const float* ow       = (const float*)d_in[26];
  const float* ob       = (const float*)d_in[27];
  float* out = (float*)d_out;

  float* ws   = (float*)d_ws;
  float* Hb   = ws;                                  // MTOK*512  (32 MB)
  float* Yb   = Hb + (size_t)MTOK * DD;              // MTOK*512  (32 MB)
  float* QKVb = Yb + (size_t)MTOK * DD;              // MTOK*1536 (96 MB)
  float* COSb = QKVb + (size_t)MTOK * 3 * DD;        // TT*32
  float* SINb = COSb + TT * 32;                      // TT*32
  int*   IDXb = (int*)(SINb + TT * 32);              // MTOK*4 ints

  dim3 blk(256);

  rope_table_k<<<(TT * 32 + 255) / 256, blk, 0, stream>>>(COSb, SINb);

  // input projection: H = x @ in_w + in_b
  gemm_k<0><<<gemm_grid(MTOK, DD), blk, 0, stream>>>(x, in_w, in_b, nullptr, Hb, MTOK, IND, DD);

  for (int l = 0; l < LL; ++l) {
    ln_k<<<MTOK / 4, blk, 0, stream>>>(Hb, ln1_s + l * DD, ln1_b + l * DD, Yb);
    gemm_k<0><<<gemm_grid(MTOK, 3 * DD), blk, 0, stream>>>(Yb, qkv_w + (size_t)l * DD * 3 * DD,
                                                           qkv_b + l * 3 * DD, nullptr, QKVb,
                                                           MTOK, DD, 3 * DD);
    rope_k<<<(BB * TT * 2 * HH * 32) / 256, blk, 0, stream>>>(QKVb, COSb, SINb);
    attn_k<<<BB * HH * (TT / 16), blk, 0, stream>>>(QKVb, Yb);
    gemm_k<1><<<gemm_grid(MTOK, DD), blk, 0, stream>>>(Yb, aout_w + (size_t)l * DD * DD,
                                                       aout_b + l * DD, Hb, Hb, MTOK, DD, DD);
    ln_k<<<MTOK / 4, blk, 0, stream>>>(Hb, ln2_s + l * DD, ln2_b + l * DD, Yb);
    gemm_k<2><<<gemm_grid(MTOK, FFNN), blk, 0, stream>>>(Yb, ff1_w + (size_t)l * DD * FFNN,
                                                         ff1_b + l * FFNN, nullptr, QKVb,
                                                         MTOK, DD, FFNN);
    gemm_k<1><<<gemm_grid(MTOK, DD), blk, 0, stream>>>(QKVb, ff2_w + (size_t)l * FFNN * DD,
                                                       ff2_b + l * DD, Hb, Hb, MTOK, FFNN, DD);
  }

  // latent projection: Z (MTOK x 256) into Yb
  gemm_k<0><<<gemm_grid(MTOK, LATD), blk, 0, stream>>>(Hb, lat_w, lat_b, nullptr, Yb, MTOK, DD, LATD);
  // VQ argmin with numpy fp32 formula
  vq32_k<<<(MTOK * 4) / 4, blk, 0, stream>>>(Yb, codebook, IDXb);
  // straight-through: st into QKVb (16 MB of its 96 MB)
  stgather_k<<<(MTOK * LATD) / 256, blk, 0, stream>>>(Yb, codebook, IDXb, QKVb);
  // unlatent: G into Hb
  gemm_k<0><<<gemm_grid(MTOK, DHH), blk, 0, stream>>>(QKVb, unlat_w, unlat_b, nullptr, Hb, MTOK, LATD, DHH);

  // decoder
  for (int l = 0; l < DLL; ++l) {
    ln_k<<<MTOK / 4, blk, 0, stream>>>(Hb, dln_s + l * DHH, dln_b + l * DHH, Yb);
    gemm_k<2><<<gemm_grid(MTOK, DFFF), blk, 0, stream>>>(Yb, dff1_w + (size_t)l * DHH * DFFF,
                                                         dff1_b + l * DFFF, nullptr, QKVb,
                                                         MTOK, DHH, DFFF);
    gemm_k<1><<<gemm_grid(MTOK, DHH), blk, 0, stream>>>(QKVb, dff2_w + (size_t)l * DFFF * DHH,
                                                        dff2_b + l * DHH, Hb, Hb, MTOK, DFFF, DHH);
  }

  gemm_k<0><<<gemm_grid(MTOK, OUTD), blk, 0, stream>>>(Hb, ow, ob, nullptr, out, MTOK, DD, OUTD);
}

// Round 6
// 12268.347 us; speedup vs baseline: 1.7285x; 1.7285x over previous
//
#include <hip/hip_runtime.h>
#include <hip/hip_bf16.h>

#define BB 32
#define TT 512
#define IND 375
#define DD 512
#define HH 8
#define HDD 64
#define LL 6
#define FFNN 1024
#define LATD 256
#define KCODES 512
#define DLL 4
#define DHH 512
#define DFFF 1024
#define OUTD 291
#define MTOK (BB*TT)   /* 16384 tokens */

// ---------------- RoPE tables (fp32) ----------------
__global__ void rope_table_k(float* __restrict__ cosb, float* __restrict__ sinb) {
  int idx = blockIdx.x * blockDim.x + threadIdx.x;
  if (idx >= TT * 32) return;
  int t = idx >> 5, i = idx & 31;
  float inv = powf(10000.0f, -(float)(2 * i) / 64.0f);
  float f = (float)t * inv;
  cosb[idx] = cosf(f);
  sinb[idx] = sinf(f);
}

// ---------------- generic fp32 GEMM, 64x64 tile (edge shapes only) ----------------
template<int EPI>
__global__ __launch_bounds__(256) void gemm_k(const float* __restrict__ A,
                                              const float* __restrict__ W,
                                              const float* __restrict__ bias,
                                              const float* __restrict__ R,
                                              float* __restrict__ C,
                                              int M, int K, int N) {
  __shared__ float As[16][65];
  __shared__ float Bs[16][64];
  const int bn = blockIdx.x * 64;
  const int bm = blockIdx.y * 64;
  const int tid = threadIdx.x;
  const int tx = tid & 15, ty = tid >> 4;
  float acc[4][4] = {};

  for (int k0 = 0; k0 < K; k0 += 16) {
    {
      int r = tid >> 2, kk = (tid & 3) << 2;
      int gr = bm + r;
#pragma unroll
      for (int j = 0; j < 4; ++j) {
        int kg = k0 + kk + j;
        As[kk + j][r] = (gr < M && kg < K) ? A[(size_t)gr * K + kg] : 0.0f;
      }
    }
    {
      int kk = tid >> 4, nn = (tid & 15) << 2;
      int kg = k0 + kk;
#pragma unroll
      for (int j = 0; j < 4; ++j) {
        int ng = bn + nn + j;
        Bs[kk][nn + j] = (kg < K && ng < N) ? W[(size_t)kg * N + ng] : 0.0f;
      }
    }
    __syncthreads();
#pragma unroll
    for (int kk = 0; kk < 16; ++kk) {
      float a0[4], b0[4];
#pragma unroll
      for (int j = 0; j < 4; ++j) { a0[j] = As[kk][ty * 4 + j]; b0[j] = Bs[kk][tx * 4 + j]; }
#pragma unroll
      for (int ii = 0; ii < 4; ++ii)
#pragma unroll
        for (int jj = 0; jj < 4; ++jj)
          acc[ii][jj] += a0[ii] * b0[jj];
    }
    __syncthreads();
  }

#pragma unroll
  for (int ii = 0; ii < 4; ++ii) {
    int m = bm + ty * 4 + ii;
    if (m >= M) continue;
#pragma unroll
    for (int jj = 0; jj < 4; ++jj) {
      int n = bn + tx * 4 + jj;
      if (n >= N) continue;
      float v = acc[ii][jj] + bias[n];
      if (EPI == 1) v += R[(size_t)m * N + n];
      if (EPI == 2) v = 0.5f * v * (1.0f + erff(v * 0.70710678118654752f));
      C[(size_t)m * N + n] = v;
    }
  }
}

// ---------------- fast fp32 GEMM, 128x128 tile, BK=16, 8x8/thread ----------------
// requires M%128==0, N%128==0, K%16==0 (no guards). Bit-identical k-order to gemm_k.
template<int EPI>
__global__ __launch_bounds__(256) void gemm128_k(const float* __restrict__ A,
                                                 const float* __restrict__ W,
                                                 const float* __restrict__ bias,
                                                 const float* __restrict__ R,
                                                 float* __restrict__ C,
                                                 int M, int K, int N) {
  __shared__ float As[16][128];          // [kk][m] transposed
  __shared__ float4 Bs4[16][2][16];      // [kk][half][tx] : float4-blocked
  const int bn = blockIdx.x * 128;
  const int bm = blockIdx.y * 128;
  const int tid = threadIdx.x;
  const int tx = tid & 15;               // n: 8 floats each
  const int ty = tid >> 4;               // m: 8 floats each
  const int ar = tid >> 1;               // A staging row 0..127
  const int ak = (tid & 1) * 8;          // A staging k offset {0,8}
  const int bk = tid >> 4;               // B staging k row 0..15
  const int bx = tid & 15;               // B staging col group

  float acc[8][8] = {};

  for (int k0 = 0; k0 < K; k0 += 16) {
    const float* ap = A + (size_t)(bm + ar) * K + k0 + ak;
    float4 a0 = *(const float4*)ap;
    float4 a1 = *(const float4*)(ap + 4);
    const float* bp = W + (size_t)(k0 + bk) * N + bn + bx * 8;
    float4 b0 = *(const float4*)bp;
    float4 b1 = *(const float4*)(bp + 4);

    __syncthreads();   // previous tile fully consumed
    As[ak + 0][ar] = a0.x; As[ak + 1][ar] = a0.y; As[ak + 2][ar] = a0.z; As[ak + 3][ar] = a0.w;
    As[ak + 4][ar] = a1.x; As[ak + 5][ar] = a1.y; As[ak + 6][ar] = a1.z; As[ak + 7][ar] = a1.w;
    Bs4[bk][0][bx] = b0;
    Bs4[bk][1][bx] = b1;
    __syncthreads();

#pragma unroll
    for (int kk = 0; kk < 16; ++kk) {
      float4 va0 = *(const float4*)&As[kk][ty * 8];
      float4 va1 = *(const float4*)&As[kk][ty * 8 + 4];
      float4 vb0 = Bs4[kk][0][tx];
      float4 vb1 = Bs4[kk][1][tx];
      float av[8] = {va0.x, va0.y, va0.z, va0.w, va1.x, va1.y, va1.z, va1.w};
      float bv[8] = {vb0.x, vb0.y, vb0.z, vb0.w, vb1.x, vb1.y, vb1.z, vb1.w};
#pragma unroll
      for (int ii = 0; ii < 8; ++ii)
#pragma unroll
        for (int jj = 0; jj < 8; ++jj)
          acc[ii][jj] = __builtin_fmaf(av[ii], bv[jj], acc[ii][jj]);
    }
  }

#pragma unroll
  for (int ii = 0; ii < 8; ++ii) {
    int m = bm + ty * 8 + ii;
#pragma unroll
    for (int g = 0; g < 2; ++g) {
      int n0 = bn + tx * 8 + g * 4;
      float4 vv;
      float t[4];
#pragma unroll
      for (int j = 0; j < 4; ++j) {
        float v = acc[ii][g * 4 + j] + bias[n0 + j];
        if (EPI == 1) v += R[(size_t)m * N + n0 + j];
        if (EPI == 2) v = 0.5f * v * (1.0f + erff(v * 0.70710678118654752f));
        t[j] = v;
      }
      vv.x = t[0]; vv.y = t[1]; vv.z = t[2]; vv.w = t[3];
      *(float4*)&C[(size_t)m * N + n0] = vv;
    }
  }
}

// ---------------- LayerNorm over D=512, wave per row ----------------
__global__ __launch_bounds__(256) void ln_k(const float* __restrict__ X,
                                            const float* __restrict__ s,
                                            const float* __restrict__ b,
                                            float* __restrict__ Y) {
  int wave = threadIdx.x >> 6, lane = threadIdx.x & 63;
  int row = blockIdx.x * 4 + wave;
  const float* x = X + (size_t)row * DD;
  float v[8];
  float sum = 0.0f;
#pragma unroll
  for (int j = 0; j < 8; ++j) { v[j] = x[lane + 64 * j]; sum += v[j]; }
#pragma unroll
  for (int o = 32; o; o >>= 1) sum += __shfl_xor(sum, o);
  float mean = sum * (1.0f / 512.0f);
  float var = 0.0f;
#pragma unroll
  for (int j = 0; j < 8; ++j) { float d = v[j] - mean; var += d * d; }
#pragma unroll
  for (int o = 32; o; o >>= 1) var += __shfl_xor(var, o);
  float inv = 1.0f / sqrtf(var * (1.0f / 512.0f) + 1e-5f);
  float* y = Y + (size_t)row * DD;
#pragma unroll
  for (int j = 0; j < 8; ++j) {
    int d = lane + 64 * j;
    y[d] = (v[j] - mean) * inv * s[d] + b[d];
  }
}

// ---------------- RoPE applied in-place to q and k sections of qkv ----------------
__global__ void rope_k(float* __restrict__ qkv, const float* __restrict__ cosb,
                       const float* __restrict__ sinb) {
  int idx = blockIdx.x * blockDim.x + threadIdx.x;  // B*T*2*H*32 = 8388608
  if (idx >= BB * TT * 2 * HH * 32) return;
  int i = idx & 31; idx >>= 5;
  int h = idx & 7;  idx >>= 3;
  int s = idx & 1;  idx >>= 1;   // 0 = q, 1 = k
  int t = idx & 511; idx >>= 9;
  int b = idx;
  size_t base = ((size_t)(b * TT + t)) * (3 * DD) + s * DD + h * HDD + 2 * i;
  float c = cosb[t * 32 + i], sn = sinb[t * 32 + i];
  float xe = qkv[base], xo = qkv[base + 1];
  qkv[base]     = xe * c - xo * sn;
  qkv[base + 1] = xe * sn + xo * c;
}

// ---------------- attention: block = (b, h, 16 q-rows) ----------------
__global__ __launch_bounds__(256) void attn_k(const float* __restrict__ qkv,
                                              float* __restrict__ out) {
  __shared__ float qs[16][65];
  __shared__ float kvs[64][65];
  __shared__ float sc[16][512];
  int bh = blockIdx.x >> 5;          // /32 q-tiles
  int qt = blockIdx.x & 31;
  int b = bh >> 3, h = bh & 7;
  int tid = threadIdx.x;
  const float* base = qkv + (size_t)b * TT * (3 * DD) + h * HDD;

  for (int e = tid; e < 16 * 64; e += 256) {
    int r = e >> 6, d = e & 63;
    qs[r][d] = base[(size_t)(qt * 16 + r) * (3 * DD) + d];
  }
  for (int kt = 0; kt < 8; ++kt) {
    __syncthreads();
    for (int e = tid; e < 64 * 64; e += 256) {
      int r = e >> 6, d = e & 63;
      kvs[r][d] = base[(size_t)(kt * 64 + r) * (3 * DD) + DD + d];
    }
    __syncthreads();
    for (int e = tid; e < 16 * 64; e += 256) {
      int r = e >> 6, c = e & 63;
      float acc = 0.0f;
#pragma unroll
      for (int d = 0; d < 64; ++d) acc += qs[r][d] * kvs[c][d];
      sc[r][kt * 64 + c] = acc * 0.125f;
    }
  }
  __syncthreads();
  int wave = tid >> 6, lane = tid & 63;
  for (int r = wave; r < 16; r += 4) {
    float vals[8];
    float m = -1e30f;
#pragma unroll
    for (int j = 0; j < 8; ++j) { vals[j] = sc[r][lane + 64 * j]; m = fmaxf(m, vals[j]); }
#pragma unroll
    for (int o = 32; o; o >>= 1) m = fmaxf(m, __shfl_xor(m, o));
    float sum = 0.0f;
#pragma unroll
    for (int j = 0; j < 8; ++j) { vals[j] = expf(vals[j] - m); sum += vals[j]; }
#pragma unroll
    for (int o = 32; o; o >>= 1) sum += __shfl_xor(sum, o);
    float inv = 1.0f / sum;
#pragma unroll
    for (int j = 0; j < 8; ++j) sc[r][lane + 64 * j] = vals[j] * inv;
  }
  float acc[4] = {0.f, 0.f, 0.f, 0.f};
  int w = wave, d = lane;
  for (int kt = 0; kt < 8; ++kt) {
    __syncthreads();
    for (int e = tid; e < 64 * 64; e += 256) {
      int r = e >> 6, dd = e & 63;
      kvs[r][dd] = base[(size_t)(kt * 64 + r) * (3 * DD) + 2 * DD + dd];
    }
    __syncthreads();
#pragma unroll
    for (int kk = 0; kk < 64; ++kk) {
      float vv = kvs[kk][d];
#pragma unroll
      for (int oi = 0; oi < 4; ++oi) acc[oi] += sc[w + 4 * oi][kt * 64 + kk] * vv;
    }
  }
#pragma unroll
  for (int oi = 0; oi < 4; ++oi) {
    int tok = b * TT + qt * 16 + w + 4 * oi;
    out[(size_t)tok * DD + h * HDD + d] = acc[oi];
  }
}

// ===== numpy pairwise-8 sum of squares of a 64-vector (strict fp32 order) =====
__device__ __forceinline__ float npsumsq64(const float* __restrict__ a) {
  float r0 = __fmul_rn(a[0], a[0]), r1 = __fmul_rn(a[1], a[1]);
  float r2 = __fmul_rn(a[2], a[2]), r3 = __fmul_rn(a[3], a[3]);
  float r4 = __fmul_rn(a[4], a[4]), r5 = __fmul_rn(a[5], a[5]);
  float r6 = __fmul_rn(a[6], a[6]), r7 = __fmul_rn(a[7], a[7]);
#pragma unroll
  for (int i = 8; i < 64; i += 8) {
    r0 = __fadd_rn(r0, __fmul_rn(a[i + 0], a[i + 0]));
    r1 = __fadd_rn(r1, __fmul_rn(a[i + 1], a[i + 1]));
    r2 = __fadd_rn(r2, __fmul_rn(a[i + 2], a[i + 2]));
    r3 = __fadd_rn(r3, __fmul_rn(a[i + 3], a[i + 3]));
    r4 = __fadd_rn(r4, __fmul_rn(a[i + 4], a[i + 4]));
    r5 = __fadd_rn(r5, __fmul_rn(a[i + 5], a[i + 5]));
    r6 = __fadd_rn(r6, __fmul_rn(a[i + 6], a[i + 6]));
    r7 = __fadd_rn(r7, __fmul_rn(a[i + 7], a[i + 7]));
  }
  return __fadd_rn(__fadd_rn(__fadd_rn(r0, r1), __fadd_rn(r2, r3)),
                   __fadd_rn(__fadd_rn(r4, r5), __fadd_rn(r6, r7)));
}

// ===== S2 precompute: one per code, bit-identical npsumsq64 =====
__global__ void vqs2_k(const float* __restrict__ CB, float* __restrict__ S2) {
  int k = blockIdx.x * 256 + threadIdx.x;
  if (k < KCODES) S2[k] = npsumsq64(CB + (size_t)k * 64);
}

// ===== VQ argmin (LDS-staged, bit-identical formula): 16 chunks / block =====
__global__ __launch_bounds__(256) void vq32b_k(const float* __restrict__ Z,
                                               const float* __restrict__ CB,
                                               const float* __restrict__ S2,
                                               int* __restrict__ idxOut) {
  __shared__ float zs[16][68];      // padded: conflict-free b128 reads
  __shared__ float cs[64][68];      // 64-code tile, padded
  __shared__ float s2s[64];
  __shared__ float rv[256];
  __shared__ int   ri[256];
  const int tid = threadIdx.x;
  const int lr = tid >> 4;          // chunk 0..15
  const int sub = tid & 15;         // 16 threads per chunk
  const int row0 = blockIdx.x * 16;

  // stage z: 16 rows x 16 float4
  {
    int r = tid >> 4, q = tid & 15;
    *(float4*)&zs[r][q * 4] = *(const float4*)(Z + (size_t)(row0 + r) * 64 + q * 4);
  }
  __syncthreads();

  const float S1 = npsumsq64(zs[lr]);

  float bv = 3.4e38f;
  int bi = 0x7fffffff;
  for (int ct = 0; ct < 8; ++ct) {
    __syncthreads();
    // stage 64 codes: 1024 float4, 4 per thread
    for (int e = tid; e < 1024; e += 256) {
      int r = e >> 4, q = e & 15;
      *(float4*)&cs[r][q * 4] = *(const float4*)(CB + (size_t)(ct * 64 + r) * 64 + q * 4);
    }
    if (tid < 64) s2s[tid] = S2[ct * 64 + tid];
    __syncthreads();
#pragma unroll
    for (int cc = 0; cc < 4; ++cc) {
      int kl = cc * 16 + sub;            // ascending k within thread
      // z . c : sequential FMA chain over d=0..63 (bit-identical order)
      float g = 0.0f;
#pragma unroll
      for (int d4 = 0; d4 < 16; ++d4) {
        float4 zf = *(const float4*)&zs[lr][d4 * 4];
        float4 cf = *(const float4*)&cs[kl][d4 * 4];
        g = __builtin_fmaf(zf.x, cf.x, g);
        g = __builtin_fmaf(zf.y, cf.y, g);
        g = __builtin_fmaf(zf.z, cf.z, g);
        g = __builtin_fmaf(zf.w, cf.w, g);
      }
      float d32 = __fadd_rn(__fsub_rn(S1, __fmul_rn(2.0f, g)), s2s[kl]);
      int k = ct * 64 + kl;
      if (d32 < bv || (d32 == bv && k < bi)) { bv = d32; bi = k; }
    }
  }
  rv[tid] = bv; ri[tid] = bi;
  __syncthreads();
  if (sub == 0) {
    float bb = rv[tid]; int ii = ri[tid];
#pragma unroll
    for (int j = 1; j < 16; ++j) {
      float v = rv[tid + j]; int id = ri[tid + j];
      if (v < bb || (v == bb && id < ii)) { bb = v; ii = id; }
    }
    idxOut[row0 + lr] = ii;
  }
}

// ===== straight-through gather: st = z + (c - z), fp32 faithful =====
__global__ void stgather_k(const float* __restrict__ Z, const float* __restrict__ CB,
                           const int* __restrict__ idx, float* __restrict__ Q) {
  int e = blockIdx.x * blockDim.x + threadIdx.x;
  if (e >= MTOK * LATD) return;
  int chunk = e >> 6, d = e & 63;
  int k = idx[chunk] & (KCODES - 1);
  float z = Z[e];
  float c = CB[(size_t)k * 64 + d];
  Q[e] = __fadd_rn(z, __fsub_rn(c, z));
}

static inline dim3 gemm_grid(int M, int N) { return dim3((N + 63) / 64, (M + 63) / 64); }
static inline dim3 g128(int M, int N) { return dim3(N / 128, M / 128); }

extern "C" void kernel_launch(void* const* d_in, const int* in_sizes, int n_in,
                              void* d_out, int out_size, void* d_ws, size_t ws_size,
                              hipStream_t stream) {
  const float* x        = (const float*)d_in[0];
  const float* in_w     = (const float*)d_in[1];
  const float* in_b     = (const float*)d_in[2];
  const float* ln1_s    = (const float*)d_in[3];
  const float* ln1_b    = (const float*)d_in[4];
  const float* qkv_w    = (const float*)d_in[5];
  const float* qkv_b    = (const float*)d_in[6];
  const float* aout_w   = (const float*)d_in[7];
  const float* aout_b   = (const float*)d_in[8];
  const float* ln2_s    = (const float*)d_in[9];
  const float* ln2_b    = (const float*)d_in[10];
  const float* ff1_w    = (const float*)d_in[11];
  const float* ff1_b    = (const float*)d_in[12];
  const float* ff2_w    = (const float*)d_in[13];
  const float* ff2_b    = (const float*)d_in[14];
  const float* lat_w    = (const float*)d_in[15];
  const float* lat_b    = (const float*)d_in[16];
  const float* codebook = (const float*)d_in[17];
  const float* unlat_w  = (const float*)d_in[18];
  const float* unlat_b  = (const float*)d_in[19];
  const float* dln_s    = (const float*)d_in[20];
  const float* dln_b    = (const float*)d_in[21];
  const float* dff1_w   = (const float*)d_in[22];
  const float* dff1_b   = (const float*)d_in[23];
  const float* dff2_w   = (const float*)d_in[24];
  const float* dff2_b   = (const float*)d_in[25];
  const float* ow       = (const float*)d_in[26];
  const float* ob       = (const float*)d_in[27];
  float* out = (float*)d_out;

  float* ws   = (float*)d_ws;
  float* Hb   = ws;                                  // MTOK*512
  float* Yb   = Hb + (size_t)MTOK * DD;              // MTOK*512
  float* QKVb = Yb + (size_t)MTOK * DD;              // MTOK*1536
  float* COSb = QKVb + (size_t)MTOK * 3 * DD;        // TT*32
  float* SINb = COSb + TT * 32;                      // TT*32
  int*   IDXb = (int*)(SINb + TT * 32);              // MTOK*4 ints
  float* S2b  = (float*)(IDXb + MTOK * 4);           // 512 floats

  dim3 blk(256);

  rope_table_k<<<(TT * 32 + 255) / 256, blk, 0, stream>>>(COSb, SINb);
  vqs2_k<<<2, blk, 0, stream>>>(codebook, S2b);

  // input projection (K=375: generic kernel)
  gemm_k<0><<<gemm_grid(MTOK, DD), blk, 0, stream>>>(x, in_w, in_b, nullptr, Hb, MTOK, IND, DD);

  for (int l = 0; l < LL; ++l) {
    ln_k<<<MTOK / 4, blk, 0, stream>>>(Hb, ln1_s + l * DD, ln1_b + l * DD, Yb);
    gemm128_k<0><<<g128(MTOK, 3 * DD), blk, 0, stream>>>(Yb, qkv_w + (size_t)l * DD * 3 * DD,
                                                         qkv_b + l * 3 * DD, nullptr, QKVb,
                                                         MTOK, DD, 3 * DD);
    rope_k<<<(BB * TT * 2 * HH * 32) / 256, blk, 0, stream>>>(QKVb, COSb, SINb);
    attn_k<<<BB * HH * (TT / 16), blk, 0, stream>>>(QKVb, Yb);
    gemm128_k<1><<<g128(MTOK, DD), blk, 0, stream>>>(Yb, aout_w + (size_t)l * DD * DD,
                                                     aout_b + l * DD, Hb, Hb, MTOK, DD, DD);
    ln_k<<<MTOK / 4, blk, 0, stream>>>(Hb, ln2_s + l * DD, ln2_b + l * DD, Yb);
    gemm128_k<2><<<g128(MTOK, FFNN), blk, 0, stream>>>(Yb, ff1_w + (size_t)l * DD * FFNN,
                                                       ff1_b + l * FFNN, nullptr, QKVb,
                                                       MTOK, DD, FFNN);
    gemm128_k<1><<<g128(MTOK, DD), blk, 0, stream>>>(QKVb, ff2_w + (size_t)l * FFNN * DD,
                                                     ff2_b + l * DD, Hb, Hb, MTOK, FFNN, DD);
  }

  // latent projection: Z into Yb
  gemm128_k<0><<<g128(MTOK, LATD), blk, 0, stream>>>(Hb, lat_w, lat_b, nullptr, Yb, MTOK, DD, LATD);
  // VQ argmin (bit-identical numpy fp32 formula)
  vq32b_k<<<(MTOK * 4) / 16, blk, 0, stream>>>(Yb, codebook, S2b, IDXb);
  stgather_k<<<(MTOK * LATD) / 256, blk, 0, stream>>>(Yb, codebook, IDXb, QKVb);
  gemm128_k<0><<<g128(MTOK, DHH), blk, 0, stream>>>(QKVb, unlat_w, unlat_b, nullptr, Hb, MTOK, LATD, DHH);

  // decoder
  for (int l = 0; l < DLL; ++l) {
    ln_k<<<MTOK / 4, blk, 0, stream>>>(Hb, dln_s + l * DHH, dln_b + l * DHH, Yb);
    gemm128_k<2><<<g128(MTOK, DFFF), blk, 0, stream>>>(Yb, dff1_w + (size_t)l * DHH * DFFF,
                                                       dff1_b + l * DFFF, nullptr, QKVb,
                                                       MTOK, DHH, DFFF);
    gemm128_k<1><<<g128(MTOK, DHH), blk, 0, stream>>>(QKVb, dff2_w + (size_t)l * DFFF * DHH,
                                                      dff2_b + l * DHH, Hb, Hb, MTOK, DFFF, DHH);
  }

  // output projection (N=291: generic kernel)
  gemm_k<0><<<gemm_grid(MTOK, OUTD), blk, 0, stream>>>(Hb, ow, ob, nullptr, out, MTOK, DD, OUTD);
}

// Round 7
// 9341.812 us; speedup vs baseline: 2.2700x; 1.3133x over previous
//
#include <hip/hip_runtime.h>
#include <hip/hip_bf16.h>

#define BB 32
#define TT 512
#define IND 375
#define DD 512
#define HH 8
#define HDD 64
#define LL 6
#define FFNN 1024
#define LATD 256
#define KCODES 512
#define DLL 4
#define DHH 512
#define DFFF 1024
#define OUTD 291
#define MTOK (BB*TT)   /* 16384 tokens */

// ---------------- RoPE tables (fp32) ----------------
__global__ void rope_table_k(float* __restrict__ cosb, float* __restrict__ sinb) {
  int idx = blockIdx.x * blockDim.x + threadIdx.x;
  if (idx >= TT * 32) return;
  int t = idx >> 5, i = idx & 31;
  float inv = powf(10000.0f, -(float)(2 * i) / 64.0f);
  float f = (float)t * inv;
  cosb[idx] = cosf(f);
  sinb[idx] = sinf(f);
}

// ---------------- generic fp32 GEMM, 64x64 tile (edge shapes only) ----------------
template<int EPI>
__global__ __launch_bounds__(256) void gemm_k(const float* __restrict__ A,
                                              const float* __restrict__ W,
                                              const float* __restrict__ bias,
                                              const float* __restrict__ R,
                                              float* __restrict__ C,
                                              int M, int K, int N) {
  __shared__ float As[16][65];
  __shared__ float Bs[16][64];
  const int bn = blockIdx.x * 64;
  const int bm = blockIdx.y * 64;
  const int tid = threadIdx.x;
  const int tx = tid & 15, ty = tid >> 4;
  float acc[4][4] = {};

  for (int k0 = 0; k0 < K; k0 += 16) {
    {
      int r = tid >> 2, kk = (tid & 3) << 2;
      int gr = bm + r;
#pragma unroll
      for (int j = 0; j < 4; ++j) {
        int kg = k0 + kk + j;
        As[kk + j][r] = (gr < M && kg < K) ? A[(size_t)gr * K + kg] : 0.0f;
      }
    }
    {
      int kk = tid >> 4, nn = (tid & 15) << 2;
      int kg = k0 + kk;
#pragma unroll
      for (int j = 0; j < 4; ++j) {
        int ng = bn + nn + j;
        Bs[kk][nn + j] = (kg < K && ng < N) ? W[(size_t)kg * N + ng] : 0.0f;
      }
    }
    __syncthreads();
#pragma unroll
    for (int kk = 0; kk < 16; ++kk) {
      float a0[4], b0[4];
#pragma unroll
      for (int j = 0; j < 4; ++j) { a0[j] = As[kk][ty * 4 + j]; b0[j] = Bs[kk][tx * 4 + j]; }
#pragma unroll
      for (int ii = 0; ii < 4; ++ii)
#pragma unroll
        for (int jj = 0; jj < 4; ++jj)
          acc[ii][jj] += a0[ii] * b0[jj];
    }
    __syncthreads();
  }

#pragma unroll
  for (int ii = 0; ii < 4; ++ii) {
    int m = bm + ty * 4 + ii;
    if (m >= M) continue;
#pragma unroll
    for (int jj = 0; jj < 4; ++jj) {
      int n = bn + tx * 4 + jj;
      if (n >= N) continue;
      float v = acc[ii][jj] + bias[n];
      if (EPI == 1) v += R[(size_t)m * N + n];
      if (EPI == 2) v = 0.5f * v * (1.0f + erff(v * 0.70710678118654752f));
      C[(size_t)m * N + n] = v;
    }
  }
}

// ---------------- fast fp32 GEMM, 128x128 tile, BK=16, 8x8/thread ----------------
// requires M%128==0, N%128==0, K%16==0 (no guards). Bit-identical k-order to gemm_k.
template<int EPI>
__global__ __launch_bounds__(256) void gemm128_k(const float* __restrict__ A,
                                                 const float* __restrict__ W,
                                                 const float* __restrict__ bias,
                                                 const float* __restrict__ R,
                                                 float* __restrict__ C,
                                                 int M, int K, int N) {
  __shared__ float As[16][128];          // [kk][m] transposed
  __shared__ float4 Bs4[16][2][16];      // [kk][half][tx] : float4-blocked
  const int bn = blockIdx.x * 128;
  const int bm = blockIdx.y * 128;
  const int tid = threadIdx.x;
  const int tx = tid & 15;               // n: 8 floats each
  const int ty = tid >> 4;               // m: 8 floats each
  const int ar = tid >> 1;               // A staging row 0..127
  const int ak = (tid & 1) * 8;          // A staging k offset {0,8}
  const int bk = tid >> 4;               // B staging k row 0..15
  const int bx = tid & 15;               // B staging col group

  float acc[8][8] = {};

  for (int k0 = 0; k0 < K; k0 += 16) {
    const float* ap = A + (size_t)(bm + ar) * K + k0 + ak;
    float4 a0 = *(const float4*)ap;
    float4 a1 = *(const float4*)(ap + 4);
    const float* bp = W + (size_t)(k0 + bk) * N + bn + bx * 8;
    float4 b0 = *(const float4*)bp;
    float4 b1 = *(const float4*)(bp + 4);

    __syncthreads();   // previous tile fully consumed
    As[ak + 0][ar] = a0.x; As[ak + 1][ar] = a0.y; As[ak + 2][ar] = a0.z; As[ak + 3][ar] = a0.w;
    As[ak + 4][ar] = a1.x; As[ak + 5][ar] = a1.y; As[ak + 6][ar] = a1.z; As[ak + 7][ar] = a1.w;
    Bs4[bk][0][bx] = b0;
    Bs4[bk][1][bx] = b1;
    __syncthreads();

#pragma unroll
    for (int kk = 0; kk < 16; ++kk) {
      float4 va0 = *(const float4*)&As[kk][ty * 8];
      float4 va1 = *(const float4*)&As[kk][ty * 8 + 4];
      float4 vb0 = Bs4[kk][0][tx];
      float4 vb1 = Bs4[kk][1][tx];
      float av[8] = {va0.x, va0.y, va0.z, va0.w, va1.x, va1.y, va1.z, va1.w};
      float bv[8] = {vb0.x, vb0.y, vb0.z, vb0.w, vb1.x, vb1.y, vb1.z, vb1.w};
#pragma unroll
      for (int ii = 0; ii < 8; ++ii)
#pragma unroll
        for (int jj = 0; jj < 8; ++jj)
          acc[ii][jj] = __builtin_fmaf(av[ii], bv[jj], acc[ii][jj]);
    }
  }

#pragma unroll
  for (int ii = 0; ii < 8; ++ii) {
    int m = bm + ty * 8 + ii;
#pragma unroll
    for (int g = 0; g < 2; ++g) {
      int n0 = bn + tx * 8 + g * 4;
      float4 vv;
      float t[4];
#pragma unroll
      for (int j = 0; j < 4; ++j) {
        float v = acc[ii][g * 4 + j] + bias[n0 + j];
        if (EPI == 1) v += R[(size_t)m * N + n0 + j];
        if (EPI == 2) v = 0.5f * v * (1.0f + erff(v * 0.70710678118654752f));
        t[j] = v;
      }
      vv.x = t[0]; vv.y = t[1]; vv.z = t[2]; vv.w = t[3];
      *(float4*)&C[(size_t)m * N + n0] = vv;
    }
  }
}

// ---------------- LayerNorm over D=512, wave per row ----------------
__global__ __launch_bounds__(256) void ln_k(const float* __restrict__ X,
                                            const float* __restrict__ s,
                                            const float* __restrict__ b,
                                            float* __restrict__ Y) {
  int wave = threadIdx.x >> 6, lane = threadIdx.x & 63;
  int row = blockIdx.x * 4 + wave;
  const float* x = X + (size_t)row * DD;
  float v[8];
  float sum = 0.0f;
#pragma unroll
  for (int j = 0; j < 8; ++j) { v[j] = x[lane + 64 * j]; sum += v[j]; }
#pragma unroll
  for (int o = 32; o; o >>= 1) sum += __shfl_xor(sum, o);
  float mean = sum * (1.0f / 512.0f);
  float var = 0.0f;
#pragma unroll
  for (int j = 0; j < 8; ++j) { float d = v[j] - mean; var += d * d; }
#pragma unroll
  for (int o = 32; o; o >>= 1) var += __shfl_xor(var, o);
  float inv = 1.0f / sqrtf(var * (1.0f / 512.0f) + 1e-5f);
  float* y = Y + (size_t)row * DD;
#pragma unroll
  for (int j = 0; j < 8; ++j) {
    int d = lane + 64 * j;
    y[d] = (v[j] - mean) * inv * s[d] + b[d];
  }
}

// ---------------- RoPE applied in-place to q and k sections of qkv ----------------
__global__ void rope_k(float* __restrict__ qkv, const float* __restrict__ cosb,
                       const float* __restrict__ sinb) {
  int idx = blockIdx.x * blockDim.x + threadIdx.x;  // B*T*2*H*32 = 8388608
  if (idx >= BB * TT * 2 * HH * 32) return;
  int i = idx & 31; idx >>= 5;
  int h = idx & 7;  idx >>= 3;
  int s = idx & 1;  idx >>= 1;   // 0 = q, 1 = k
  int t = idx & 511; idx >>= 9;
  int b = idx;
  size_t base = ((size_t)(b * TT + t)) * (3 * DD) + s * DD + h * HDD + 2 * i;
  float c = cosb[t * 32 + i], sn = sinb[t * 32 + i];
  float xe = qkv[base], xo = qkv[base + 1];
  qkv[base]     = xe * c - xo * sn;
  qkv[base + 1] = xe * sn + xo * c;
}

// ---------------- flash attention: block = (b, h, 64 q-rows) ----------------
// 16x16 thread grid, 4x4 output tile per thread, online softmax.
__global__ __launch_bounds__(256) void fattn_k(const float* __restrict__ qkv,
                                               float* __restrict__ out) {
  __shared__ float Qs[64][68];   // [d][r]   (k-major)
  __shared__ float KVs[64][68];  // K phase: [d][c] ; V phase: [c][dv]
  __shared__ float Ps[64][68];   // [c][r]
  const int tid = threadIdx.x;
  const int tx = tid & 15, ty = tid >> 4;
  const int qt = blockIdx.x & 7;
  const int h  = (blockIdx.x >> 3) & 7;
  const int b  = blockIdx.x >> 6;
  const float* base = qkv + (size_t)b * TT * (3 * DD) + h * HDD;

  // stage Q tile transposed [d][r]; lane r consecutive -> conflict-free LDS writes,
  // strided global reads absorbed by L1 across the 4 waves.
  {
    int r = tid & 63, q0 = tid >> 6;
#pragma unroll
    for (int jj = 0; jj < 4; ++jj) {
      int q = q0 + jj * 4;
      float4 v = *(const float4*)(base + (size_t)(qt * 64 + r) * (3 * DD) + q * 4);
      Qs[q * 4 + 0][r] = v.x; Qs[q * 4 + 1][r] = v.y;
      Qs[q * 4 + 2][r] = v.z; Qs[q * 4 + 3][r] = v.w;
    }
  }

  float o[4][4] = {};
  float m[4] = {-1e30f, -1e30f, -1e30f, -1e30f};
  float l[4] = {0.f, 0.f, 0.f, 0.f};

  for (int kt = 0; kt < 8; ++kt) {
    __syncthreads();   // prev PV done (Ps/KVs free)
    // stage K tile [d][c]
    {
      int r = tid & 63, q0 = tid >> 6;
#pragma unroll
      for (int jj = 0; jj < 4; ++jj) {
        int q = q0 + jj * 4;
        float4 v = *(const float4*)(base + (size_t)(kt * 64 + r) * (3 * DD) + DD + q * 4);
        KVs[q * 4 + 0][r] = v.x; KVs[q * 4 + 1][r] = v.y;
        KVs[q * 4 + 2][r] = v.z; KVs[q * 4 + 3][r] = v.w;
      }
    }
    __syncthreads();

    // scores: s[i][j] = sum_d Q[ty*4+i][d] * K[tx*4+j][d]
    float s[4][4] = {};
#pragma unroll 4
    for (int d = 0; d < 64; ++d) {
      float4 a4 = *(const float4*)&Qs[d][ty * 4];
      float4 b4 = *(const float4*)&KVs[d][tx * 4];
      float av[4] = {a4.x, a4.y, a4.z, a4.w};
      float bv[4] = {b4.x, b4.y, b4.z, b4.w};
#pragma unroll
      for (int ii = 0; ii < 4; ++ii)
#pragma unroll
        for (int jj = 0; jj < 4; ++jj)
          s[ii][jj] = __builtin_fmaf(av[ii], bv[jj], s[ii][jj]);
    }

    // online softmax (per 4-row group across 16 tx lanes)
#pragma unroll
    for (int i = 0; i < 4; ++i) {
      float mm = fmaxf(fmaxf(s[i][0], s[i][1]), fmaxf(s[i][2], s[i][3])) * 0.125f;
#pragma unroll
      for (int off = 1; off < 16; off <<= 1) mm = fmaxf(mm, __shfl_xor(mm, off));
      float mn = fmaxf(m[i], mm);
      float f = expf(m[i] - mn);
      m[i] = mn;
      float ls = 0.0f;
#pragma unroll
      for (int j = 0; j < 4; ++j) {
        float p = expf(__builtin_fmaf(s[i][j], 0.125f, -mn));
        s[i][j] = p;
        ls += p;
      }
#pragma unroll
      for (int off = 1; off < 16; off <<= 1) ls += __shfl_xor(ls, off);
      l[i] = __builtin_fmaf(l[i], f, ls);
#pragma unroll
      for (int j = 0; j < 4; ++j) o[i][j] *= f;
    }

    __syncthreads();   // K reads done -> KVs reusable for V

    // write P to Ps[c][r] as 4x b128 (2-way conflict)
#pragma unroll
    for (int j = 0; j < 4; ++j) {
      float4 pv; pv.x = s[0][j]; pv.y = s[1][j]; pv.z = s[2][j]; pv.w = s[3][j];
      *(float4*)&Ps[tx * 4 + j][ty * 4] = pv;
    }
    // stage V tile [c][dv] row-major, coalesced
#pragma unroll
    for (int ii = 0; ii < 4; ++ii) {
      int e = tid + 256 * ii;
      int c = e >> 4, q = e & 15;
      float4 v = *(const float4*)(base + (size_t)(kt * 64 + c) * (3 * DD) + 2 * DD + q * 4);
      *(float4*)&KVs[c][q * 4] = v;
    }
    __syncthreads();

    // PV: o[i][j] += sum_c P[ty*4+i][c] * V[c][tx*4+j]
#pragma unroll 4
    for (int c = 0; c < 64; ++c) {
      float4 a4 = *(const float4*)&Ps[c][ty * 4];
      float4 b4 = *(const float4*)&KVs[c][tx * 4];
      float av[4] = {a4.x, a4.y, a4.z, a4.w};
      float bv[4] = {b4.x, b4.y, b4.z, b4.w};
#pragma unroll
      for (int ii = 0; ii < 4; ++ii)
#pragma unroll
        for (int jj = 0; jj < 4; ++jj)
          o[ii][jj] = __builtin_fmaf(av[ii], bv[jj], o[ii][jj]);
    }
  }

  // epilogue: out[tok][h*64 + dv] = o / l
#pragma unroll
  for (int i = 0; i < 4; ++i) {
    float inv = 1.0f / l[i];
    int tok = b * TT + qt * 64 + ty * 4 + i;
    float4 vv;
    vv.x = o[i][0] * inv; vv.y = o[i][1] * inv;
    vv.z = o[i][2] * inv; vv.w = o[i][3] * inv;
    *(float4*)&out[(size_t)tok * DD + h * HDD + tx * 4] = vv;
  }
}

// ===== numpy pairwise-8 sum of squares of a 64-vector (strict fp32 order) =====
__device__ __forceinline__ float npsumsq64(const float* __restrict__ a) {
  float r0 = __fmul_rn(a[0], a[0]), r1 = __fmul_rn(a[1], a[1]);
  float r2 = __fmul_rn(a[2], a[2]), r3 = __fmul_rn(a[3], a[3]);
  float r4 = __fmul_rn(a[4], a[4]), r5 = __fmul_rn(a[5], a[5]);
  float r6 = __fmul_rn(a[6], a[6]), r7 = __fmul_rn(a[7], a[7]);
#pragma unroll
  for (int i = 8; i < 64; i += 8) {
    r0 = __fadd_rn(r0, __fmul_rn(a[i + 0], a[i + 0]));
    r1 = __fadd_rn(r1, __fmul_rn(a[i + 1], a[i + 1]));
    r2 = __fadd_rn(r2, __fmul_rn(a[i + 2], a[i + 2]));
    r3 = __fadd_rn(r3, __fmul_rn(a[i + 3], a[i + 3]));
    r4 = __fadd_rn(r4, __fmul_rn(a[i + 4], a[i + 4]));
    r5 = __fadd_rn(r5, __fmul_rn(a[i + 5], a[i + 5]));
    r6 = __fadd_rn(r6, __fmul_rn(a[i + 6], a[i + 6]));
    r7 = __fadd_rn(r7, __fmul_rn(a[i + 7], a[i + 7]));
  }
  return __fadd_rn(__fadd_rn(__fadd_rn(r0, r1), __fadd_rn(r2, r3)),
                   __fadd_rn(__fadd_rn(r4, r5), __fadd_rn(r6, r7)));
}

// ===== S2 precompute: one per code, bit-identical npsumsq64 =====
__global__ void vqs2_k(const float* __restrict__ CB, float* __restrict__ S2) {
  int k = blockIdx.x * 256 + threadIdx.x;
  if (k < KCODES) S2[k] = npsumsq64(CB + (size_t)k * 64);
}

// ===== VQ argmin (LDS-staged, bit-identical formula): 16 chunks / block =====
__global__ __launch_bounds__(256) void vq32b_k(const float* __restrict__ Z,
                                               const float* __restrict__ CB,
                                               const float* __restrict__ S2,
                                               int* __restrict__ idxOut) {
  __shared__ float zs[16][68];
  __shared__ float cs[64][68];
  __shared__ float s2s[64];
  __shared__ float rv[256];
  __shared__ int   ri[256];
  const int tid = threadIdx.x;
  const int lr = tid >> 4;
  const int sub = tid & 15;
  const int row0 = blockIdx.x * 16;

  {
    int r = tid >> 4, q = tid & 15;
    *(float4*)&zs[r][q * 4] = *(const float4*)(Z + (size_t)(row0 + r) * 64 + q * 4);
  }
  __syncthreads();

  const float S1 = npsumsq64(zs[lr]);

  float bv = 3.4e38f;
  int bi = 0x7fffffff;
  for (int ct = 0; ct < 8; ++ct) {
    __syncthreads();
    for (int e = tid; e < 1024; e += 256) {
      int r = e >> 4, q = e & 15;
      *(float4*)&cs[r][q * 4] = *(const float4*)(CB + (size_t)(ct * 64 + r) * 64 + q * 4);
    }
    if (tid < 64) s2s[tid] = S2[ct * 64 + tid];
    __syncthreads();
#pragma unroll
    for (int cc = 0; cc < 4; ++cc) {
      int kl = cc * 16 + sub;
      float g = 0.0f;
#pragma unroll
      for (int d4 = 0; d4 < 16; ++d4) {
        float4 zf = *(const float4*)&zs[lr][d4 * 4];
        float4 cf = *(const float4*)&cs[kl][d4 * 4];
        g = __builtin_fmaf(zf.x, cf.x, g);
        g = __builtin_fmaf(zf.y, cf.y, g);
        g = __builtin_fmaf(zf.z, cf.z, g);
        g = __builtin_fmaf(zf.w, cf.w, g);
      }
      float d32 = __fadd_rn(__fsub_rn(S1, __fmul_rn(2.0f, g)), s2s[kl]);
      int k = ct * 64 + kl;
      if (d32 < bv || (d32 == bv && k < bi)) { bv = d32; bi = k; }
    }
  }
  rv[tid] = bv; ri[tid] = bi;
  __syncthreads();
  if (sub == 0) {
    float bb = rv[tid]; int ii = ri[tid];
#pragma unroll
    for (int j = 1; j < 16; ++j) {
      float v = rv[tid + j]; int id = ri[tid + j];
      if (v < bb || (v == bb && id < ii)) { bb = v; ii = id; }
    }
    idxOut[row0 + lr] = ii;
  }
}

// ===== straight-through gather: st = z + (c - z), fp32 faithful =====
__global__ void stgather_k(const float* __restrict__ Z, const float* __restrict__ CB,
                           const int* __restrict__ idx, float* __restrict__ Q) {
  int e = blockIdx.x * blockDim.x + threadIdx.x;
  if (e >= MTOK * LATD) return;
  int chunk = e >> 6, d = e & 63;
  int k = idx[chunk] & (KCODES - 1);
  float z = Z[e];
  float c = CB[(size_t)k * 64 + d];
  Q[e] = __fadd_rn(z, __fsub_rn(c, z));
}

static inline dim3 gemm_grid(int M, int N) { return dim3((N + 63) / 64, (M + 63) / 64); }
static inline dim3 g128(int M, int N) { return dim3(N / 128, M / 128); }

extern "C" void kernel_launch(void* const* d_in, const int* in_sizes, int n_in,
                              void* d_out, int out_size, void* d_ws, size_t ws_size,
                              hipStream_t stream) {
  const float* x        = (const float*)d_in[0];
  const float* in_w     = (const float*)d_in[1];
  const float* in_b     = (const float*)d_in[2];
  const float* ln1_s    = (const float*)d_in[3];
  const float* ln1_b    = (const float*)d_in[4];
  const float* qkv_w    = (const float*)d_in[5];
  const float* qkv_b    = (const float*)d_in[6];
  const float* aout_w   = (const float*)d_in[7];
  const float* aout_b   = (const float*)d_in[8];
  const float* ln2_s    = (const float*)d_in[9];
  const float* ln2_b    = (const float*)d_in[10];
  const float* ff1_w    = (const float*)d_in[11];
  const float* ff1_b    = (const float*)d_in[12];
  const float* ff2_w    = (const float*)d_in[13];
  const float* ff2_b    = (const float*)d_in[14];
  const float* lat_w    = (const float*)d_in[15];
  const float* lat_b    = (const float*)d_in[16];
  const float* codebook = (const float*)d_in[17];
  const float* unlat_w  = (const float*)d_in[18];
  const float* unlat_b  = (const float*)d_in[19];
  const float* dln_s    = (const float*)d_in[20];
  const float* dln_b    = (const float*)d_in[21];
  const float* dff1_w   = (const float*)d_in[22];
  const float* dff1_b   = (const float*)d_in[23];
  const float* dff2_w   = (const float*)d_in[24];
  const float* dff2_b   = (const float*)d_in[25];
  const float* ow       = (const float*)d_in[26];
  const float* ob       = (const float*)d_in[27];
  float* out = (float*)d_out;

  float* ws   = (float*)d_ws;
  float* Hb   = ws;                                  // MTOK*512
  float* Yb   = Hb + (size_t)MTOK * DD;              // MTOK*512
  float* QKVb = Yb + (size_t)MTOK * DD;              // MTOK*1536
  float* COSb = QKVb + (size_t)MTOK * 3 * DD;        // TT*32
  float* SINb = COSb + TT * 32;                      // TT*32
  int*   IDXb = (int*)(SINb + TT * 32);              // MTOK*4 ints
  float* S2b  = (float*)(IDXb + MTOK * 4);           // 512 floats

  dim3 blk(256);

  rope_table_k<<<(TT * 32 + 255) / 256, blk, 0, stream>>>(COSb, SINb);
  vqs2_k<<<2, blk, 0, stream>>>(codebook, S2b);

  // input projection (K=375: generic kernel)
  gemm_k<0><<<gemm_grid(MTOK, DD), blk, 0, stream>>>(x, in_w, in_b, nullptr, Hb, MTOK, IND, DD);

  for (int l = 0; l < LL; ++l) {
    ln_k<<<MTOK / 4, blk, 0, stream>>>(Hb, ln1_s + l * DD, ln1_b + l * DD, Yb);
    gemm128_k<0><<<g128(MTOK, 3 * DD), blk, 0, stream>>>(Yb, qkv_w + (size_t)l * DD * 3 * DD,
                                                         qkv_b + l * 3 * DD, nullptr, QKVb,
                                                         MTOK, DD, 3 * DD);
    rope_k<<<(BB * TT * 2 * HH * 32) / 256, blk, 0, stream>>>(QKVb, COSb, SINb);
    fattn_k<<<BB * HH * (TT / 64), blk, 0, stream>>>(QKVb, Yb);
    gemm128_k<1><<<g128(MTOK, DD), blk, 0, stream>>>(Yb, aout_w + (size_t)l * DD * DD,
                                                     aout_b + l * DD, Hb, Hb, MTOK, DD, DD);
    ln_k<<<MTOK / 4, blk, 0, stream>>>(Hb, ln2_s + l * DD, ln2_b + l * DD, Yb);
    gemm128_k<2><<<g128(MTOK, FFNN), blk, 0, stream>>>(Yb, ff1_w + (size_t)l * DD * FFNN,
                                                       ff1_b + l * FFNN, nullptr, QKVb,
                                                       MTOK, DD, FFNN);
    gemm128_k<1><<<g128(MTOK, DD), blk, 0, stream>>>(QKVb, ff2_w + (size_t)l * FFNN * DD,
                                                     ff2_b + l * DD, Hb, Hb, MTOK, FFNN, DD);
  }

  // latent projection: Z into Yb
  gemm128_k<0><<<g128(MTOK, LATD), blk, 0, stream>>>(Hb, lat_w, lat_b, nullptr, Yb, MTOK, DD, LATD);
  // VQ argmin (bit-identical numpy fp32 formula)
  vq32b_k<<<(MTOK * 4) / 16, blk, 0, stream>>>(Yb, codebook, S2b, IDXb);
  stgather_k<<<(MTOK * LATD) / 256, blk, 0, stream>>>(Yb, codebook, IDXb, QKVb);
  gemm128_k<0><<<g128(MTOK, DHH), blk, 0, stream>>>(QKVb, unlat_w, unlat_b, nullptr, Hb, MTOK, LATD, DHH);

  // decoder
  for (int l = 0; l < DLL; ++l) {
    ln_k<<<MTOK / 4, blk, 0, stream>>>(Hb, dln_s + l * DHH, dln_b + l * DHH, Yb);
    gemm128_k<2><<<g128(MTOK, DFFF), blk, 0, stream>>>(Yb, dff1_w + (size_t)l * DHH * DFFF,
                                                       dff1_b + l * DFFF, nullptr, QKVb,
                                                       MTOK, DHH, DFFF);
    gemm128_k<1><<<g128(MTOK, DHH), blk, 0, stream>>>(QKVb, dff2_w + (size_t)l * DFFF * DHH,
                                                      dff2_b + l * DHH, Hb, Hb, MTOK, DFFF, DHH);
  }

  // output projection (N=291: generic kernel)
  gemm_k<0><<<gemm_grid(MTOK, OUTD), blk, 0, stream>>>(Hb, ow, ob, nullptr, out, MTOK, DD, OUTD);
}